// Round 1
// baseline (783.103 us; speedup 1.0000x reference)
//
#include <hip/hip_runtime.h>
#include <hip/hip_bf16.h>

// GraphSAGE 2-layer, N=100000, E=1.6M, D=128. f32 I/O, bf16 MFMA compute.
//
// R9: XCD-pinned feature-sliced aggregation.
//   Old agg: wave/node 256B-row gathers from a 25.6MB table -> 56% L2 miss,
//   179MB through the ~2.6TB/s L3 random-line path = 69us plateau.
//   New agg: 8 slices x 16 bf16 (32B rows, 3.2MB table/slice). Slice s is
//   processed by XCD s (HW_REG_XCC_ID read in-kernel + per-slice chunk
//   counters, cross-slice stealing for correctness under any mapping).
//   Gathers become 32B L2-HIT requests: ~1.6M req/XCD @ ~16/cy = ~42us,
//   FETCH drops to compulsory ~85MB. Requires slice-major bf16 layout
//   [8][N][8 u32] for xb / Aagg / h1b (gemm re-addressed accordingly;
//   fragment loads stay 16B-aligned and wave-contiguous).
//
// Pipeline (9 dispatches): memset bucketCnt -> bucket_count -> bucket_scan
//   (also zeroes agg work counters) -> partition+wprep -> csr_build+cvt ->
//   agg1 -> gemm1(relu->h1b) -> agg2 -> gemm2 -> d_out f32.
//   Fallback layout B (small ws): f32 node-major gathers, h1 f32 in d_out.

typedef __attribute__((ext_vector_type(8))) short short8;
typedef __attribute__((ext_vector_type(4))) float float4_;
typedef __attribute__((ext_vector_type(4))) unsigned int uint4_;

#define NBMAX 512  // max buckets (256 nodes each) -> N <= 131072

__device__ __forceinline__ unsigned short f2bf(float f) {
    unsigned int u = __float_as_uint(f);
    unsigned int r = (u + 0x7FFFu + ((u >> 16) & 1u)) >> 16;
    return (unsigned short)r;
}

// ---------------- phase 1a: bucket histogram (bucket = dst >> 8) -----------
__global__ __launch_bounds__(256) void bucket_count(const int* __restrict__ dst, int E, int NB,
                                                    int* __restrict__ bucketCnt) {
    __shared__ int h[NBMAX];
    int tid = threadIdx.x;
    for (int b = tid; b < NB; b += 256) h[b] = 0;
    __syncthreads();
    int base = blockIdx.x * 4096;
    for (int i = 0; i < 16; i++) {
        int e = base + i * 256 + tid;
        if (e < E) atomicAdd(&h[dst[e] >> 8], 1);
    }
    __syncthreads();
    for (int b = tid; b < NB; b += 256)
        if (h[b]) atomicAdd(&bucketCnt[b], h[b]);
}

// ---------------- phase 1b: scan bucket counts (1 block) -------------------
__global__ __launch_bounds__(512) void bucket_scan(const int* __restrict__ bucketCnt, int NB,
                                                   int* __restrict__ bucketOffs,
                                                   int* __restrict__ bucketCur,
                                                   int* __restrict__ aggCtr) {
    __shared__ int sd[512];
    int t = threadIdx.x;
    if (t < 16) aggCtr[t] = 0;  // work counters for the two sliced aggs
    int v = (t < NB) ? bucketCnt[t] : 0;
    sd[t] = v;
    __syncthreads();
    for (int off = 1; off < 512; off <<= 1) {
        int x = sd[t];
        int y = (t >= off) ? sd[t - off] : 0;
        __syncthreads();
        sd[t] = x + y;
        __syncthreads();
    }
    int excl = sd[t] - v;
    if (t <= NB) bucketOffs[t] = excl;  // bucketOffs[NB] = E sentinel
    if (t < NB) bucketCur[t] = excl;
}

// ---------------- phase 1c: partition edges + (tail blocks) weight prep ----
__global__ __launch_bounds__(256) void partition_wprep(
    const int* __restrict__ src, const int* __restrict__ dst, int E, int NB, int partBlocks,
    int* __restrict__ bucketCur, unsigned int* __restrict__ bucketBuf,
    const float* __restrict__ Wn1, const float* __restrict__ Ws1,
    const float* __restrict__ bn1, const float* __restrict__ bs1,
    const float* __restrict__ Wn2, const float* __restrict__ Ws2,
    const float* __restrict__ bn2, const float* __restrict__ bs2,
    unsigned short* __restrict__ Bpre, float* __restrict__ biasPre) {
    int tid = threadIdx.x;
    if ((int)blockIdx.x >= partBlocks) {
        // ---- weight prep: f32 W -> bf16 pre-swizzled fragments ----
        int wb = blockIdx.x - partBlocks;  // [0,32)
        int l = wb >> 4;
        const float* Wn = l ? Wn2 : Wn1;
        const float* Ws = l ? Ws2 : Ws1;
        int fi = (wb & 15) * 256 + tid;
        int kt = fi >> 9;
        int nt = (fi >> 6) & 7;
        int lane = fi & 63;
        int o = nt * 16 + (lane & 15);
        int k = kt * 32 + (lane >> 4) * 8;
        const float* srcp = (k < 128) ? (Wn + o * 128 + k) : (Ws + o * 128 + (k - 128));
        short8 v;
#pragma unroll
        for (int j = 0; j < 8; j++) v[j] = (short)f2bf(srcp[j]);
        ((short8*)(Bpre + (size_t)l * 32768))[fi] = v;
        if ((wb & 15) == 0 && tid < 128) {
            const float* bn = l ? bn2 : bn1;
            const float* bs = l ? bs2 : bs1;
            biasPre[l * 128 + tid] = bn[tid] + bs[tid];
        }
        return;
    }
    __shared__ int cnt[NBMAX];
    __shared__ int base[NBMAX];
    for (int b = tid; b < NB; b += 256) cnt[b] = 0;
    __syncthreads();
    int eb = blockIdx.x * 4096;
    unsigned int pk[16];
    int bk[16], rk[16];
    for (int i = 0; i < 16; i++) {
        int e = eb + i * 256 + tid;
        if (e < E) {
            int d = dst[e];
            bk[i] = d >> 8;
            pk[i] = (unsigned)src[e] | ((unsigned)(d & 255) << 24);
            rk[i] = atomicAdd(&cnt[bk[i]], 1);
        } else {
            bk[i] = -1;
        }
    }
    __syncthreads();
    for (int b = tid; b < NB; b += 256)
        base[b] = cnt[b] ? atomicAdd(&bucketCur[b], cnt[b]) : 0;
    __syncthreads();
    for (int i = 0; i < 16; i++)
        if (bk[i] >= 0) bucketBuf[base[bk[i]] + rk[i]] = pk[i];
}

// ---------------- phase 2: per-bucket CSR build + (tail blocks) x->bf16 ----
// cvt now writes xb SLICE-MAJOR: [slice 0..7][node][8 u32] (32B per
// node-slice). Thread p -> (n = p>>3, s = p&7): reads 64B of x row n,
// writes one 32B chunk; per wave both sides fully coalesced.
__global__ __launch_bounds__(256) void csrbuild_cvt(
    const unsigned int* __restrict__ bucketBuf, const int* __restrict__ bucketOffs,
    int N, int NB, int* __restrict__ deg, int* __restrict__ offs, int* __restrict__ sortedSrc,
    const float* __restrict__ xin, unsigned int* __restrict__ xb, int Np) {
    int tid = threadIdx.x;
    if ((int)blockIdx.x >= NB) {
        int cb = blockIdx.x - NB;
        int p = cb * 256 + tid;
        if (xb && p < Np) {
            int n = p >> 3;
            int s = p & 7;
            const float* xr = xin + (size_t)n * 128 + s * 16;
            float4_ f0 = *(const float4_*)(xr);
            float4_ f1 = *(const float4_*)(xr + 4);
            float4_ f2 = *(const float4_*)(xr + 8);
            float4_ f3 = *(const float4_*)(xr + 12);
            uint4_ qa, qb;
            qa[0] = (unsigned)f2bf(f0[0]) | ((unsigned)f2bf(f0[1]) << 16);
            qa[1] = (unsigned)f2bf(f0[2]) | ((unsigned)f2bf(f0[3]) << 16);
            qa[2] = (unsigned)f2bf(f1[0]) | ((unsigned)f2bf(f1[1]) << 16);
            qa[3] = (unsigned)f2bf(f1[2]) | ((unsigned)f2bf(f1[3]) << 16);
            qb[0] = (unsigned)f2bf(f2[0]) | ((unsigned)f2bf(f2[1]) << 16);
            qb[1] = (unsigned)f2bf(f2[2]) | ((unsigned)f2bf(f2[3]) << 16);
            qb[2] = (unsigned)f2bf(f3[0]) | ((unsigned)f2bf(f3[1]) << 16);
            qb[3] = (unsigned)f2bf(f3[2]) | ((unsigned)f2bf(f3[3]) << 16);
            unsigned int* ob = xb + ((size_t)s * N + n) * 8;
            *(uint4_*)ob = qa;
            *(uint4_*)(ob + 4) = qb;
        }
        return;
    }
    __shared__ int h[256];
    __shared__ int sc[256];
    __shared__ int cur[256];
    int b = blockIdx.x;
    int n0 = b << 8;
    int bo = bucketOffs[b];
    int cnt = bucketOffs[b + 1] - bo;
    h[tid] = 0;
    __syncthreads();
    for (int i = tid; i < cnt; i += 256) atomicAdd(&h[bucketBuf[bo + i] >> 24], 1);
    __syncthreads();
    int v = h[tid];
    sc[tid] = v;
    __syncthreads();
    for (int off = 1; off < 256; off <<= 1) {
        int x = sc[tid];
        int y = (tid >= off) ? sc[tid - off] : 0;
        __syncthreads();
        sc[tid] = x + y;
        __syncthreads();
    }
    int excl = sc[tid] - v;
    cur[tid] = bo + excl;
    int n = n0 + tid;
    if (n < N) {
        deg[n] = v;
        offs[n] = bo + excl;
    }
    __syncthreads();
    for (int i = tid; i < cnt; i += 256) {
        unsigned int pv = bucketBuf[bo + i];
        int pos = atomicAdd(&cur[pv >> 24], 1);
        sortedSrc[pos] = (int)(pv & 0xFFFFFFu);
    }
}

// ---------------- XCD-pinned sliced mean agg (bf16, slice-major) -----------
// table/out: [8][Nn][8 u32]. Block: 256 thr = 32 nodes x 8 lanes; each lane
// owns one u32 (2 bf16) of a 16-feature slice. Chunk = 128 nodes, edge list
// staged in LDS (contiguous in sortedSrc since nodes are consecutive).
// Slice selection: own XCD's slice first (L2-resident 3.2MB table), then
// steal from other slices so any block->XCD mapping stays correct.
#define AGG_CHN 128
__global__ __launch_bounds__(256) void agg_sliced(
    const unsigned int* __restrict__ table, const int* __restrict__ deg,
    const int* __restrict__ offs, const int* __restrict__ sortedSrc,
    unsigned int* __restrict__ out, int Nn, int* __restrict__ ctr) {
    __shared__ int eb[4608];
    __shared__ int chunkS;
    int tid = threadIdx.x;
    int xcc;
    asm volatile("s_getreg_b32 %0, hwreg(HW_REG_XCC_ID)" : "=s"(xcc));
    int nChunks = (Nn + AGG_CHN - 1) / AGG_CHN;
    int g = tid & 7;
    for (int pass = 0; pass < 8; ++pass) {
        int s = (xcc + pass) & 7;
        const unsigned int* tb = table + (size_t)s * Nn * 8;
        unsigned int* ob = out + (size_t)s * Nn * 8;
        for (;;) {
            __syncthreads();  // prior chunk's eb reads + chunkS read done
            if (tid == 0) chunkS = atomicAdd(&ctr[s], 1);
            __syncthreads();
            int c = chunkS;
            if (c >= nChunks) break;  // uniform
            int n0 = c * AGG_CHN;
            int last = min(n0 + AGG_CHN, Nn) - 1;
            int lo = offs[n0];
            int cnt = offs[last] + deg[last] - lo;
            bool fits = (cnt <= 4608);
            if (fits)
                for (int i = tid; i < cnt; i += 256) eb[i] = sortedSrc[lo + i];
            __syncthreads();
#pragma unroll
            for (int ph = 0; ph < AGG_CHN / 32; ++ph) {
                int n = n0 + ph * 32 + (tid >> 3);
                if (n <= last) {
                    int d = deg[n];
                    int st = offs[n] - lo;
                    float a0 = 0.f, a1 = 0.f;
                    if (fits) {
                        int j = 0;
                        for (; j + 8 <= d; j += 8) {
                            unsigned int v[8];
#pragma unroll
                            for (int u = 0; u < 8; ++u)
                                v[u] = tb[(size_t)eb[st + j + u] * 8 + g];
#pragma unroll
                            for (int u = 0; u < 8; ++u) {
                                a0 += __uint_as_float(v[u] << 16);
                                a1 += __uint_as_float(v[u] & 0xFFFF0000u);
                            }
                        }
                        for (; j < d; ++j) {
                            unsigned int u = tb[(size_t)eb[st + j] * 8 + g];
                            a0 += __uint_as_float(u << 16);
                            a1 += __uint_as_float(u & 0xFFFF0000u);
                        }
                    } else {  // overflow fallback (astronomically rare)
                        for (int j = 0; j < d; ++j) {
                            unsigned int u = tb[(size_t)sortedSrc[lo + st + j] * 8 + g];
                            a0 += __uint_as_float(u << 16);
                            a1 += __uint_as_float(u & 0xFFFF0000u);
                        }
                    }
                    float inv = 1.0f / (float)max(d, 1);
                    ob[(size_t)n * 8 + g] =
                        (unsigned)f2bf(a0 * inv) | ((unsigned)f2bf(a1 * inv) << 16);
                }
            }
        }
    }
}

// ---------------- mean agg, f32 source (fallback layout B, node-major) -----
__global__ __launch_bounds__(256) void agg_f32_kernel(
    const float* __restrict__ srcFeats,
    const int* __restrict__ deg, const int* __restrict__ offs,
    const int* __restrict__ sortedSrc,
    unsigned int* __restrict__ dst, int Nn) {
    int wave = threadIdx.x >> 6, lane = threadIdx.x & 63;
    int n = blockIdx.x * 4 + wave;
    if (n >= Nn) return;
    int d = deg[n], st = offs[n];
    float a0 = 0.f, a1 = 0.f;
    int j = 0;
    for (; j + 8 <= d; j += 8) {
        float2 v[8];
#pragma unroll
        for (int u = 0; u < 8; u++) {
            int s = __builtin_amdgcn_readfirstlane(sortedSrc[st + j + u]);
            v[u] = ((const float2*)(srcFeats + (size_t)s * 128))[lane];
        }
#pragma unroll
        for (int u = 0; u < 8; u++) {
            a0 += v[u].x;
            a1 += v[u].y;
        }
    }
    for (; j < d; j++) {
        int s = __builtin_amdgcn_readfirstlane(sortedSrc[st + j]);
        float2 v = ((const float2*)(srcFeats + (size_t)s * 128))[lane];
        a0 += v.x;
        a1 += v.y;
    }
    float inv = 1.0f / (float)max(d, 1);
    dst[(size_t)n * 64 + lane] = (unsigned)f2bf(a0 * inv) | ((unsigned)f2bf(a1 * inv) << 16);
}

// slice-major bf16 fragment load: short8 at (row, kk), kk%16 in {0,8}
__device__ __forceinline__ short8 loadS8s(const unsigned short* base, int Nn, int row, int kk) {
    return *(const short8*)(base + ((size_t)(kk >> 4) * Nn + (size_t)row) * 16 + (kk & 15));
}

// ---------------- fused GEMM: out = act([Aagg|Aself] @ B^T + bias) ---------
// sliced=1: Aagg / bf16 Aself / bf16 Out are slice-major [8][N][16 u16].
// sliced=0 (fallback layout B): node-major, f32 self, f32 out.
// Out may alias Aself (fallback layer 2): each wave reads only its own 32
// rows before writing them -> safe. (No __restrict__ on Aself/Out.)
__global__ __launch_bounds__(256) void gemm_kernel(
    const unsigned short* __restrict__ Aagg, const void* Aself,
    const unsigned short* __restrict__ Bpre, const float* __restrict__ biasPre,
    void* Out, int relu, int selfF32, int outBf16, int sliced, int Nrows) {
    __shared__ unsigned short ldsB[8 * 8 * 64 * 8];  // 64 KB
    __shared__ float biasS[128];
    int tid = threadIdx.x;

    // Pure coalesced copy: Bpre is already bf16 in fragment order.
#pragma unroll
    for (int i = 0; i < 16; i++) {
        int fi = tid + 256 * i;
        ((short8*)ldsB)[fi] = ((const short8*)Bpre)[fi];
    }
    if (tid < 128) biasS[tid] = biasPre[tid];
    __syncthreads();

    int wave = tid >> 6, lane = tid & 63;
    int quad = lane >> 4, mr = lane & 15;
    int rowBase = blockIdx.x * 128 + wave * 32;

    float4_ acc[2][8];
    float4_ z = {0.f, 0.f, 0.f, 0.f};
    for (int mt = 0; mt < 2; mt++)
        for (int nt = 0; nt < 8; nt++) acc[mt][nt] = z;

    for (int kt = 0; kt < 8; kt++) {
        int kk = (kt & 3) * 32 + quad * 8;
        short8 a[2];
        for (int mt = 0; mt < 2; mt++) {
            int row = rowBase + mt * 16 + mr;
            if (row >= Nrows) row = Nrows - 1;  // in-bounds; result discarded
            if (kt < 4) {
                a[mt] = sliced ? loadS8s(Aagg, Nrows, row, kk)
                               : *(const short8*)(Aagg + (size_t)row * 128 + kk);
            } else if (selfF32) {
                const float* p = (const float*)Aself + (size_t)row * 128 + kk;
                float4_ f0 = *(const float4_*)p;
                float4_ f1 = *(const float4_*)(p + 4);
                short8 t;
#pragma unroll
                for (int j = 0; j < 4; j++) {
                    t[j] = (short)f2bf(f0[j]);
                    t[4 + j] = (short)f2bf(f1[j]);
                }
                a[mt] = t;
            } else {
                a[mt] = loadS8s((const unsigned short*)Aself, Nrows, row, kk);
            }
        }
        for (int nt = 0; nt < 8; nt++) {
            short8 b = *(const short8*)(ldsB + ((size_t)(kt * 8 + nt) * 64 + lane) * 8);
            acc[0][nt] = __builtin_amdgcn_mfma_f32_16x16x32_bf16(a[0], b, acc[0][nt], 0, 0, 0);
            acc[1][nt] = __builtin_amdgcn_mfma_f32_16x16x32_bf16(a[1], b, acc[1][nt], 0, 0, 0);
        }
    }

    // C/D layout: col = lane&15, row = (lane>>4)*4 + reg
    for (int mt = 0; mt < 2; mt++) {
        for (int nt = 0; nt < 8; nt++) {
            int col = nt * 16 + mr;
            float bv = biasS[col];
            for (int r = 0; r < 4; r++) {
                int row = rowBase + mt * 16 + quad * 4 + r;
                if (row < Nrows) {
                    float v = acc[mt][nt][r] + bv;
                    if (relu) v = fmaxf(v, 0.f);
                    if (outBf16)  // bf16 out only used in sliced path -> slice-major
                        ((unsigned short*)Out)[((size_t)nt * Nrows + row) * 16 + mr] = f2bf(v);
                    else
                        ((float*)Out)[(size_t)row * 128 + col] = v;
                }
            }
        }
    }
}

extern "C" void kernel_launch(void* const* d_in, const int* in_sizes, int n_in,
                              void* d_out, int out_size, void* d_ws, size_t ws_size,
                              hipStream_t stream) {
    const float* x = (const float*)d_in[0];
    const int* ei = (const int*)d_in[1];
    const float* Wn1 = (const float*)d_in[2];
    const float* bn1 = (const float*)d_in[3];
    const float* Ws1 = (const float*)d_in[4];
    const float* bs1 = (const float*)d_in[5];
    const float* Wn2 = (const float*)d_in[6];
    const float* bn2 = (const float*)d_in[7];
    const float* Ws2 = (const float*)d_in[8];
    const float* bs2 = (const float*)d_in[9];

    const int N = in_sizes[0] / 128;
    const int E = in_sizes[1] / 2;
    const int* srcI = ei;
    const int* dstI = ei + E;
    const int NB = (N + 255) >> 8;  // <= NBMAX for N <= 131072

    char* ws = (char*)d_ws;
    size_t off = 0;
    auto alloc = [&](size_t bytes) -> void* {
        void* p = ws + off;
        off += (bytes + 255) & ~(size_t)255;
        return p;
    };
    int* deg = (int*)alloc((size_t)N * 4);
    int* offs = (int*)alloc((size_t)N * 4);
    int* bucketCnt = (int*)alloc((NBMAX + 1) * 4);
    int* bucketOffs = (int*)alloc((NBMAX + 1) * 4);
    int* bucketCur = (int*)alloc((NBMAX + 1) * 4);
    int* aggCtr = (int*)alloc(16 * 4);
    unsigned short* Bpre = (unsigned short*)alloc(2 * 32768 * 2);
    float* biasPre = (float*)alloc(2 * 128 * 4);
    int* sortedSrc = (int*)alloc((size_t)E * 4);
    unsigned short* Aagg = (unsigned short*)alloc((size_t)N * 128 * 2);
    size_t baseNeed = off;
    size_t bf16Buf = ((size_t)N * 128 * 2 + 255) & ~(size_t)255;
    bool bigWs = (ws_size >= baseNeed + 2 * bf16Buf);
    unsigned int* xb = nullptr;
    unsigned short* h1b = nullptr;
    if (bigWs) {
        xb = (unsigned int*)alloc((size_t)N * 128 * 2);
        h1b = (unsigned short*)alloc((size_t)N * 128 * 2);
    }
    // bucketBuf (E u32, 6.4 MB) aliases Aagg (dead until agg1)
    unsigned int* bucketBuf = (unsigned int*)Aagg;

    // ---- CSR build + overlapped wprep/cvt ----
    int ebBlocks = (E + 4095) / 4096;
    int Np = N * 8;  // (node, slice) pairs for cvt
    int cvtBlocks = bigWs ? (Np + 255) / 256 : 0;
    hipMemsetAsync(bucketCnt, 0, (size_t)NB * 4, stream);
    bucket_count<<<ebBlocks, 256, 0, stream>>>(dstI, E, NB, bucketCnt);
    bucket_scan<<<1, 512, 0, stream>>>(bucketCnt, NB, bucketOffs, bucketCur, aggCtr);
    partition_wprep<<<ebBlocks + 32, 256, 0, stream>>>(
        srcI, dstI, E, NB, ebBlocks, bucketCur, bucketBuf,
        Wn1, Ws1, bn1, bs1, Wn2, Ws2, bn2, bs2, Bpre, biasPre);
    csrbuild_cvt<<<NB + cvtBlocks, 256, 0, stream>>>(bucketBuf, bucketOffs, N, NB, deg, offs,
                                                     sortedSrc, x, xb, Np);

    int gemmBlocks = (N + 127) / 128;
    int aggGrid = 2048;  // 8 blocks/CU; blocks self-schedule via aggCtr

    if (bigWs) {
        // Layout A: sliced bf16 gathers (32B rows, L2-resident per XCD)
        agg_sliced<<<aggGrid, 256, 0, stream>>>(xb, deg, offs, sortedSrc,
                                                (unsigned int*)Aagg, N, aggCtr);
        gemm_kernel<<<gemmBlocks, 256, 0, stream>>>(Aagg, xb, Bpre, biasPre, h1b,
                                                    1, 0, 1, 1, N);
        agg_sliced<<<aggGrid, 256, 0, stream>>>((const unsigned int*)h1b, deg, offs, sortedSrc,
                                                (unsigned int*)Aagg, N, aggCtr + 8);
        gemm_kernel<<<gemmBlocks, 256, 0, stream>>>(Aagg, h1b, Bpre + 32768, biasPre + 128,
                                                    d_out, 0, 0, 0, 1, N);
    } else {
        // Layout B: f32 node-major gathers, h1 f32 staged in d_out
        int aggBlocks = (N + 3) / 4;
        float* h1 = (float*)d_out;
        agg_f32_kernel<<<aggBlocks, 256, 0, stream>>>(x, deg, offs, sortedSrc,
                                                      (unsigned int*)Aagg, N);
        gemm_kernel<<<gemmBlocks, 256, 0, stream>>>(Aagg, x, Bpre, biasPre, h1,
                                                    1, 1, 0, 0, N);
        agg_f32_kernel<<<aggBlocks, 256, 0, stream>>>(h1, deg, offs, sortedSrc,
                                                      (unsigned int*)Aagg, N);
        gemm_kernel<<<gemmBlocks, 256, 0, stream>>>(Aagg, h1, Bpre + 32768, biasPre + 128,
                                                    d_out, 0, 1, 0, 0, N);
    }
}

// Round 2
// 427.286 us; speedup vs baseline: 1.8327x; 1.8327x over previous
//
#include <hip/hip_runtime.h>
#include <hip/hip_bf16.h>

// GraphSAGE 2-layer, N=100000, E=1.6M, D=128. f32 I/O, bf16 MFMA compute.
//
// R10: fused agg+GEMM. R9 lesson (measured): gather cost currency is
// CACHE-LINE FILLS per CU, capped at ~0.073 fills/cy/CU regardless of hit
// tier (R8: 3.2M fills/69us; R9 sliced: 12.8M fills/289us -> same rate).
// So agg's floor is E*2 fills = ~69us/layer and can't drop via L2 tricks.
// Instead, hide the GEMM inside that fill-stall time: one persistent-block
// kernel per layer does {gather-agg 32-row tile -> LDS (swizzled) ->
// MFMA vs resident 64KB B -> epilogue}. 2 blocks/CU (72.7KB LDS): block A's
// MFMA overlaps block B's fills. Deletes 2 gemm dispatches + Aagg global
// round-trip (~51MB) + 2 gaps. Gather pattern = proven R8 (node-major bf16,
// wave/node, 16-deep, readfirstlane SGPR row bases).
//
// Pipeline (7 dispatches): memset bucketCnt -> bucket_count -> bucket_scan
//   (also zeroes tile counters) -> partition+wprep -> csr_build+cvt ->
//   fused1 (relu, bf16 h1b) -> fused2 (f32 d_out).
//   Fallback layout B (small ws): f32 gathers, separate gemm, h1 in d_out.

typedef __attribute__((ext_vector_type(8))) short short8;
typedef __attribute__((ext_vector_type(4))) float float4_;

#define NBMAX 512  // max buckets (256 nodes each) -> N <= 131072

__device__ __forceinline__ unsigned short f2bf(float f) {
    unsigned int u = __float_as_uint(f);
    unsigned int r = (u + 0x7FFFu + ((u >> 16) & 1u)) >> 16;
    return (unsigned short)r;
}

// ---------------- phase 1a: bucket histogram (bucket = dst >> 8) -----------
__global__ __launch_bounds__(256) void bucket_count(const int* __restrict__ dst, int E, int NB,
                                                    int* __restrict__ bucketCnt) {
    __shared__ int h[NBMAX];
    int tid = threadIdx.x;
    for (int b = tid; b < NB; b += 256) h[b] = 0;
    __syncthreads();
    int base = blockIdx.x * 4096;
    for (int i = 0; i < 16; i++) {
        int e = base + i * 256 + tid;
        if (e < E) atomicAdd(&h[dst[e] >> 8], 1);
    }
    __syncthreads();
    for (int b = tid; b < NB; b += 256)
        if (h[b]) atomicAdd(&bucketCnt[b], h[b]);
}

// ---------------- phase 1b: scan bucket counts (1 block) -------------------
__global__ __launch_bounds__(512) void bucket_scan(const int* __restrict__ bucketCnt, int NB,
                                                   int* __restrict__ bucketOffs,
                                                   int* __restrict__ bucketCur,
                                                   int* __restrict__ tileCtr) {
    __shared__ int sd[512];
    int t = threadIdx.x;
    if (t < 16) tileCtr[t] = 0;  // dynamic tile counters for the two fused layers
    int v = (t < NB) ? bucketCnt[t] : 0;
    sd[t] = v;
    __syncthreads();
    for (int off = 1; off < 512; off <<= 1) {
        int x = sd[t];
        int y = (t >= off) ? sd[t - off] : 0;
        __syncthreads();
        sd[t] = x + y;
        __syncthreads();
    }
    int excl = sd[t] - v;
    if (t <= NB) bucketOffs[t] = excl;  // bucketOffs[NB] = E sentinel
    if (t < NB) bucketCur[t] = excl;
}

// ---------------- phase 1c: partition edges + (tail blocks) weight prep ----
__global__ __launch_bounds__(256) void partition_wprep(
    const int* __restrict__ src, const int* __restrict__ dst, int E, int NB, int partBlocks,
    int* __restrict__ bucketCur, unsigned int* __restrict__ bucketBuf,
    const float* __restrict__ Wn1, const float* __restrict__ Ws1,
    const float* __restrict__ bn1, const float* __restrict__ bs1,
    const float* __restrict__ Wn2, const float* __restrict__ Ws2,
    const float* __restrict__ bn2, const float* __restrict__ bs2,
    unsigned short* __restrict__ Bpre, float* __restrict__ biasPre) {
    int tid = threadIdx.x;
    if ((int)blockIdx.x >= partBlocks) {
        // ---- weight prep: f32 W -> bf16 pre-swizzled fragments ----
        int wb = blockIdx.x - partBlocks;  // [0,32)
        int l = wb >> 4;
        const float* Wn = l ? Wn2 : Wn1;
        const float* Ws = l ? Ws2 : Ws1;
        int fi = (wb & 15) * 256 + tid;
        int kt = fi >> 9;
        int nt = (fi >> 6) & 7;
        int lane = fi & 63;
        int o = nt * 16 + (lane & 15);
        int k = kt * 32 + (lane >> 4) * 8;
        const float* srcp = (k < 128) ? (Wn + o * 128 + k) : (Ws + o * 128 + (k - 128));
        short8 v;
#pragma unroll
        for (int j = 0; j < 8; j++) v[j] = (short)f2bf(srcp[j]);
        ((short8*)(Bpre + (size_t)l * 32768))[fi] = v;
        if ((wb & 15) == 0 && tid < 128) {
            const float* bn = l ? bn2 : bn1;
            const float* bs = l ? bs2 : bs1;
            biasPre[l * 128 + tid] = bn[tid] + bs[tid];
        }
        return;
    }
    __shared__ int cnt[NBMAX];
    __shared__ int base[NBMAX];
    for (int b = tid; b < NB; b += 256) cnt[b] = 0;
    __syncthreads();
    int eb = blockIdx.x * 4096;
    unsigned int pk[16];
    int bk[16], rk[16];
    for (int i = 0; i < 16; i++) {
        int e = eb + i * 256 + tid;
        if (e < E) {
            int d = dst[e];
            bk[i] = d >> 8;
            pk[i] = (unsigned)src[e] | ((unsigned)(d & 255) << 24);
            rk[i] = atomicAdd(&cnt[bk[i]], 1);
        } else {
            bk[i] = -1;
        }
    }
    __syncthreads();
    for (int b = tid; b < NB; b += 256)
        base[b] = cnt[b] ? atomicAdd(&bucketCur[b], cnt[b]) : 0;
    __syncthreads();
    for (int i = 0; i < 16; i++)
        if (bk[i] >= 0) bucketBuf[base[bk[i]] + rk[i]] = pk[i];
}

// ---------------- phase 2: per-bucket CSR build + (tail blocks) x->bf16 ----
__global__ __launch_bounds__(256) void csrbuild_cvt(
    const unsigned int* __restrict__ bucketBuf, const int* __restrict__ bucketOffs,
    int N, int NB, int* __restrict__ deg, int* __restrict__ offs, int* __restrict__ sortedSrc,
    const float* __restrict__ xin, unsigned int* __restrict__ xb, int n2) {
    int tid = threadIdx.x;
    if ((int)blockIdx.x >= NB) {
        // ---- cvt: f32 [N,128] -> packed bf16 u32 [N,64], 8 u32/thread ----
        int cb = blockIdx.x - NB;
        int base = cb * 2048 + tid;
        if (xb) {
#pragma unroll
            for (int i = 0; i < 8; i++) {
                int t = base + i * 256;
                if (t < n2) {
                    float2 v = ((const float2*)xin)[t];
                    xb[t] = (unsigned)f2bf(v.x) | ((unsigned)f2bf(v.y) << 16);
                }
            }
        }
        return;
    }
    __shared__ int h[256];
    __shared__ int sc[256];
    __shared__ int cur[256];
    int b = blockIdx.x;
    int n0 = b << 8;
    int bo = bucketOffs[b];
    int cnt = bucketOffs[b + 1] - bo;
    h[tid] = 0;
    __syncthreads();
    for (int i = tid; i < cnt; i += 256) atomicAdd(&h[bucketBuf[bo + i] >> 24], 1);
    __syncthreads();
    int v = h[tid];
    sc[tid] = v;
    __syncthreads();
    for (int off = 1; off < 256; off <<= 1) {
        int x = sc[tid];
        int y = (tid >= off) ? sc[tid - off] : 0;
        __syncthreads();
        sc[tid] = x + y;
        __syncthreads();
    }
    int excl = sc[tid] - v;
    cur[tid] = bo + excl;
    int n = n0 + tid;
    if (n < N) {
        deg[n] = v;
        offs[n] = bo + excl;
    }
    __syncthreads();
    for (int i = tid; i < cnt; i += 256) {
        unsigned int pv = bucketBuf[bo + i];
        int pos = atomicAdd(&cur[pv >> 24], 1);
        sortedSrc[pos] = (int)(pv & 0xFFFFFFu);
    }
}

// ---------------- fused layer: agg (gather-mean) + GEMM + bias + act -------
// table: node-major packed bf16 [N][64 u32] (features 2l, 2l+1 in u32 l).
// Per tile (32 rows): 8 waves x 4 nodes gather-aggregate -> swizzled LDS A
// (u32 idx = lane ^ ((r&7)<<2), kills the stride-256B bank conflict on the
// consume-side ds_read_b128) -> barrier -> MFMA vs 64KB resident B -> out.
// out = act([agg | self] @ B^T + bias); layer1: relu+bf16 h1b, layer2: f32.
__global__ __launch_bounds__(512) void fused_layer(
    const unsigned int* __restrict__ table,
    const int* __restrict__ deg, const int* __restrict__ offs,
    const int* __restrict__ sortedSrc,
    const unsigned short* __restrict__ Bpre, const float* __restrict__ biasPre,
    void* Out, int relu, int outBf16, int Nrows, int* __restrict__ ctr) {
    __shared__ unsigned short ldsB[32768];  // 64 KB
    __shared__ unsigned int ldsA[32 * 64];  // 8 KB, swizzled
    __shared__ float biasS[128];
    __shared__ int tileS;
    int tid = threadIdx.x;

    // B copy: Bpre already bf16 in fragment order; coalesced.
#pragma unroll
    for (int i = 0; i < 8; i++) {
        int fi = tid + 512 * i;
        ((short8*)ldsB)[fi] = ((const short8*)Bpre)[fi];
    }
    if (tid < 128) biasS[tid] = biasPre[tid];

    int wave = tid >> 6, lane = tid & 63;
    int quad = lane >> 4, mr = lane & 15;
    int nTiles = (Nrows + 31) >> 5;
    const unsigned short* selfT = (const unsigned short*)table;

    for (;;) {
        __syncthreads();  // ldsA reuse + tileS reuse (also covers B copy, iter 0)
        if (tid == 0) tileS = atomicAdd(ctr, 1);
        __syncthreads();
        int t = tileS;
        if (t >= nTiles) break;  // uniform
        int base = t << 5;

        // ---- produce: wave w aggregates nodes base + w*4 + [0,4) ----
        for (int i = 0; i < 4; i++) {
            int r = wave * 4 + i;
            int n = base + r;
            if (n < Nrows) {
                int d = deg[n], st = offs[n];
                float a0 = 0.f, a1 = 0.f;
                int j = 0;
                for (; j + 16 <= d; j += 16) {
                    unsigned int uu[16];
#pragma unroll
                    for (int u = 0; u < 16; u++) {
                        int s = __builtin_amdgcn_readfirstlane(sortedSrc[st + j + u]);
                        uu[u] = (table + (size_t)s * 64)[lane];
                    }
#pragma unroll
                    for (int u = 0; u < 16; u++) {
                        a0 += __uint_as_float(uu[u] << 16);
                        a1 += __uint_as_float(uu[u] & 0xFFFF0000u);
                    }
                }
                for (; j + 8 <= d; j += 8) {
                    unsigned int uu[8];
#pragma unroll
                    for (int u = 0; u < 8; u++) {
                        int s = __builtin_amdgcn_readfirstlane(sortedSrc[st + j + u]);
                        uu[u] = (table + (size_t)s * 64)[lane];
                    }
#pragma unroll
                    for (int u = 0; u < 8; u++) {
                        a0 += __uint_as_float(uu[u] << 16);
                        a1 += __uint_as_float(uu[u] & 0xFFFF0000u);
                    }
                }
                for (; j < d; j++) {
                    int s = __builtin_amdgcn_readfirstlane(sortedSrc[st + j]);
                    unsigned int u = (table + (size_t)s * 64)[lane];
                    a0 += __uint_as_float(u << 16);
                    a1 += __uint_as_float(u & 0xFFFF0000u);
                }
                float inv = 1.0f / (float)max(d, 1);
                unsigned int pv = (unsigned)f2bf(a0 * inv) | ((unsigned)f2bf(a1 * inv) << 16);
                ldsA[(r << 6) + (lane ^ ((r & 7) << 2))] = pv;
            }
        }
        __syncthreads();

        // ---- consume: wave w -> rows (w&1)*16, cols (w>>1)*32 ----
        int rBase = (wave & 1) << 4;
        int nt0 = (wave >> 1) << 1;
        float4_ z = {0.f, 0.f, 0.f, 0.f};
        float4_ acc[2];
        acc[0] = z;
        acc[1] = z;
        for (int kt = 0; kt < 8; kt++) {
            int kk = (kt & 3) * 32 + quad * 8;
            short8 a;
            if (kt < 4) {
                int r = rBase + mr;
                a = *(const short8*)&ldsA[(r << 6) + ((kk >> 1) ^ ((r & 7) << 2))];
            } else {
                int row = base + rBase + mr;
                if (row >= Nrows) row = Nrows - 1;  // in-bounds; result discarded
                a = *(const short8*)(selfT + (size_t)row * 128 + kk);
            }
#pragma unroll
            for (int q = 0; q < 2; q++) {
                short8 b = *(const short8*)(ldsB + ((size_t)(kt * 8 + nt0 + q) * 64 + lane) * 8);
                acc[q] = __builtin_amdgcn_mfma_f32_16x16x32_bf16(a, b, acc[q], 0, 0, 0);
            }
        }
        // C/D layout: col = lane&15, row = (lane>>4)*4 + reg
#pragma unroll
        for (int q = 0; q < 2; q++) {
            int col = (nt0 + q) * 16 + mr;
            float bv = biasS[col];
#pragma unroll
            for (int rr = 0; rr < 4; rr++) {
                int row = base + rBase + quad * 4 + rr;
                if (row < Nrows) {
                    float v = acc[q][rr] + bv;
                    if (relu) v = fmaxf(v, 0.f);
                    if (outBf16)
                        ((unsigned short*)Out)[(size_t)row * 128 + col] = f2bf(v);
                    else
                        ((float*)Out)[(size_t)row * 128 + col] = v;
                }
            }
        }
    }
}

// ---------------- mean agg, f32 source (fallback layout B) ------------------
__global__ __launch_bounds__(256) void agg_f32_kernel(
    const float* __restrict__ srcFeats,
    const int* __restrict__ deg, const int* __restrict__ offs,
    const int* __restrict__ sortedSrc,
    unsigned int* __restrict__ dst, int Nn) {
    int wave = threadIdx.x >> 6, lane = threadIdx.x & 63;
    int n = blockIdx.x * 4 + wave;
    if (n >= Nn) return;
    int d = deg[n], st = offs[n];
    float a0 = 0.f, a1 = 0.f;
    int j = 0;
    for (; j + 8 <= d; j += 8) {
        float2 v[8];
#pragma unroll
        for (int u = 0; u < 8; u++) {
            int s = __builtin_amdgcn_readfirstlane(sortedSrc[st + j + u]);
            v[u] = ((const float2*)(srcFeats + (size_t)s * 128))[lane];
        }
#pragma unroll
        for (int u = 0; u < 8; u++) {
            a0 += v[u].x;
            a1 += v[u].y;
        }
    }
    for (; j < d; j++) {
        int s = __builtin_amdgcn_readfirstlane(sortedSrc[st + j]);
        float2 v = ((const float2*)(srcFeats + (size_t)s * 128))[lane];
        a0 += v.x;
        a1 += v.y;
    }
    float inv = 1.0f / (float)max(d, 1);
    dst[(size_t)n * 64 + lane] = (unsigned)f2bf(a0 * inv) | ((unsigned)f2bf(a1 * inv) << 16);
}

// ---------------- fallback GEMM (layout B): node-major, f32 self -----------
// Out may alias Aself (layer 2): each wave reads only its own 32 rows before
// writing them -> safe. (No __restrict__ on Aself/Out.)
__global__ __launch_bounds__(256) void gemm_kernel(
    const unsigned short* __restrict__ Aagg, const void* Aself,
    const unsigned short* __restrict__ Bpre, const float* __restrict__ biasPre,
    void* Out, int relu, int selfF32, int outBf16, int Nrows) {
    __shared__ unsigned short ldsB[8 * 8 * 64 * 8];  // 64 KB
    __shared__ float biasS[128];
    int tid = threadIdx.x;
#pragma unroll
    for (int i = 0; i < 16; i++) {
        int fi = tid + 256 * i;
        ((short8*)ldsB)[fi] = ((const short8*)Bpre)[fi];
    }
    if (tid < 128) biasS[tid] = biasPre[tid];
    __syncthreads();

    int wave = tid >> 6, lane = tid & 63;
    int quad = lane >> 4, mr = lane & 15;
    int rowBase = blockIdx.x * 128 + wave * 32;

    float4_ acc[2][8];
    float4_ z = {0.f, 0.f, 0.f, 0.f};
    for (int mt = 0; mt < 2; mt++)
        for (int nt = 0; nt < 8; nt++) acc[mt][nt] = z;

    for (int kt = 0; kt < 8; kt++) {
        int kk = (kt & 3) * 32 + quad * 8;
        short8 a[2];
        for (int mt = 0; mt < 2; mt++) {
            int row = rowBase + mt * 16 + mr;
            if (row >= Nrows) row = Nrows - 1;
            if (kt < 4) {
                a[mt] = *(const short8*)(Aagg + (size_t)row * 128 + kk);
            } else if (selfF32) {
                const float* p = (const float*)Aself + (size_t)row * 128 + kk;
                float4_ f0 = *(const float4_*)p;
                float4_ f1 = *(const float4_*)(p + 4);
                short8 tt;
#pragma unroll
                for (int j = 0; j < 4; j++) {
                    tt[j] = (short)f2bf(f0[j]);
                    tt[4 + j] = (short)f2bf(f1[j]);
                }
                a[mt] = tt;
            } else {
                a[mt] = *(const short8*)((const unsigned short*)Aself + (size_t)row * 128 + kk);
            }
        }
        for (int nt = 0; nt < 8; nt++) {
            short8 b = *(const short8*)(ldsB + ((size_t)(kt * 8 + nt) * 64 + lane) * 8);
            acc[0][nt] = __builtin_amdgcn_mfma_f32_16x16x32_bf16(a[0], b, acc[0][nt], 0, 0, 0);
            acc[1][nt] = __builtin_amdgcn_mfma_f32_16x16x32_bf16(a[1], b, acc[1][nt], 0, 0, 0);
        }
    }
    for (int mt = 0; mt < 2; mt++) {
        for (int nt = 0; nt < 8; nt++) {
            int col = nt * 16 + mr;
            float bv = biasS[col];
            for (int r = 0; r < 4; r++) {
                int row = rowBase + mt * 16 + quad * 4 + r;
                if (row < Nrows) {
                    float v = acc[mt][nt][r] + bv;
                    if (relu) v = fmaxf(v, 0.f);
                    if (outBf16)
                        ((unsigned short*)Out)[(size_t)row * 128 + col] = f2bf(v);
                    else
                        ((float*)Out)[(size_t)row * 128 + col] = v;
                }
            }
        }
    }
}

extern "C" void kernel_launch(void* const* d_in, const int* in_sizes, int n_in,
                              void* d_out, int out_size, void* d_ws, size_t ws_size,
                              hipStream_t stream) {
    const float* x = (const float*)d_in[0];
    const int* ei = (const int*)d_in[1];
    const float* Wn1 = (const float*)d_in[2];
    const float* bn1 = (const float*)d_in[3];
    const float* Ws1 = (const float*)d_in[4];
    const float* bs1 = (const float*)d_in[5];
    const float* Wn2 = (const float*)d_in[6];
    const float* bn2 = (const float*)d_in[7];
    const float* Ws2 = (const float*)d_in[8];
    const float* bs2 = (const float*)d_in[9];

    const int N = in_sizes[0] / 128;
    const int E = in_sizes[1] / 2;
    const int* srcI = ei;
    const int* dstI = ei + E;
    const int NB = (N + 255) >> 8;  // <= NBMAX for N <= 131072

    char* ws = (char*)d_ws;
    size_t off = 0;
    auto alloc = [&](size_t bytes) -> void* {
        void* p = ws + off;
        off += (bytes + 255) & ~(size_t)255;
        return p;
    };
    int* deg = (int*)alloc((size_t)N * 4);
    int* offs = (int*)alloc((size_t)N * 4);
    int* bucketCnt = (int*)alloc((NBMAX + 1) * 4);
    int* bucketOffs = (int*)alloc((NBMAX + 1) * 4);
    int* bucketCur = (int*)alloc((NBMAX + 1) * 4);
    int* tileCtr = (int*)alloc(16 * 4);
    unsigned short* Bpre = (unsigned short*)alloc(2 * 32768 * 2);
    float* biasPre = (float*)alloc(2 * 128 * 4);
    int* sortedSrc = (int*)alloc((size_t)E * 4);
    unsigned short* Aagg = (unsigned short*)alloc((size_t)N * 128 * 2);
    size_t baseNeed = off;
    size_t bf16Buf = ((size_t)N * 128 * 2 + 255) & ~(size_t)255;
    bool bigWs = (ws_size >= baseNeed + 2 * bf16Buf);
    unsigned int* xb = nullptr;
    unsigned short* h1b = nullptr;
    if (bigWs) {
        xb = (unsigned int*)alloc((size_t)N * 128 * 2);
        h1b = (unsigned short*)alloc((size_t)N * 128 * 2);
    }
    // bucketBuf (E u32, 6.4 MB) aliases Aagg (dead until agg; unused in fused path)
    unsigned int* bucketBuf = (unsigned int*)Aagg;

    // ---- CSR build + overlapped wprep/cvt ----
    int ebBlocks = (E + 4095) / 4096;
    int n2 = N * 64;
    int cvtBlocks = bigWs ? (n2 + 2047) / 2048 : 0;
    hipMemsetAsync(bucketCnt, 0, (size_t)NB * 4, stream);
    bucket_count<<<ebBlocks, 256, 0, stream>>>(dstI, E, NB, bucketCnt);
    bucket_scan<<<1, 512, 0, stream>>>(bucketCnt, NB, bucketOffs, bucketCur, tileCtr);
    partition_wprep<<<ebBlocks + 32, 256, 0, stream>>>(
        srcI, dstI, E, NB, ebBlocks, bucketCur, bucketBuf,
        Wn1, Ws1, bn1, bs1, Wn2, Ws2, bn2, bs2, Bpre, biasPre);
    csrbuild_cvt<<<NB + cvtBlocks, 256, 0, stream>>>(bucketBuf, bucketOffs, N, NB, deg, offs,
                                                     sortedSrc, x, xb, n2);

    if (bigWs) {
        // Fused path: 512 persistent blocks (2/CU, 72.7KB LDS), dynamic tiles.
        fused_layer<<<512, 512, 0, stream>>>(xb, deg, offs, sortedSrc, Bpre, biasPre,
                                             h1b, 1, 1, N, tileCtr);
        fused_layer<<<512, 512, 0, stream>>>((const unsigned int*)h1b, deg, offs, sortedSrc,
                                             Bpre + 32768, biasPre + 128,
                                             d_out, 0, 0, N, tileCtr + 8);
    } else {
        // Layout B: f32 gathers, h1 f32 staged in d_out
        int aggBlocks = (N + 3) / 4;
        int gemmBlocks = (N + 127) / 128;
        float* h1 = (float*)d_out;
        agg_f32_kernel<<<aggBlocks, 256, 0, stream>>>(x, deg, offs, sortedSrc,
                                                      (unsigned int*)Aagg, N);
        gemm_kernel<<<gemmBlocks, 256, 0, stream>>>(Aagg, x, Bpre, biasPre, h1, 1, 1, 0, N);
        agg_f32_kernel<<<aggBlocks, 256, 0, stream>>>(h1, deg, offs, sortedSrc,
                                                      (unsigned int*)Aagg, N);
        gemm_kernel<<<gemmBlocks, 256, 0, stream>>>(Aagg, h1, Bpre + 32768, biasPre + 128,
                                                    d_out, 0, 1, 0, N);
    }
}

// Round 3
// 361.797 us; speedup vs baseline: 2.1645x; 1.1810x over previous
//
#include <hip/hip_runtime.h>
#include <hip/hip_bf16.h>

// GraphSAGE 2-layer, N=100000, E=1.6M, D=128. f32 I/O, bf16 MFMA compute.
//
// R11: revert to R8 agg/gemm (R10 fusion post-mortem: barrier-phased gather
// dropped L1-fill BW 5.9->3.1 TB/s; agg alone at 69.4us IS the fill-BW
// roofline: E*256B = 410MB at the measured ~5.9TB/s line-fill ceiling).
// New target: CSR pipeline (+gaps) ~150us inferred from R10 totals. Theory:
// partition/csrbuild are bound by random 4B scatter stores (1 transaction
// per lane). Fix: LDS-restage both scatters so global writes are
// run-coalesced (partition: stage (val,addr) sorted by bucket, linear
// writeout; csrbuild: sort into LDS by dst rank, stream sortedSrc[bo+i]).
//
// Pipeline (9 dispatches): memset bucketCnt -> bucket_count -> bucket_scan ->
//   partition+wprep -> csr_build+cvt -> agg1 -> gemm1(relu->h1b) -> agg2 ->
//   gemm2 -> d_out f32.  Fallback layout B (small ws): f32 gathers, h1 f32
//   staged in d_out.

typedef __attribute__((ext_vector_type(8))) short short8;
typedef __attribute__((ext_vector_type(4))) float float4_;

#define NBMAX 512  // max buckets (256 nodes each) -> N <= 131072

__device__ __forceinline__ unsigned short f2bf(float f) {
    unsigned int u = __float_as_uint(f);
    unsigned int r = (u + 0x7FFFu + ((u >> 16) & 1u)) >> 16;
    return (unsigned short)r;
}

// ---------------- phase 1a: bucket histogram (bucket = dst >> 8) -----------
__global__ __launch_bounds__(256) void bucket_count(const int* __restrict__ dst, int E, int NB,
                                                    int* __restrict__ bucketCnt) {
    __shared__ int h[NBMAX];
    int tid = threadIdx.x;
    for (int b = tid; b < NB; b += 256) h[b] = 0;
    __syncthreads();
    int base = blockIdx.x * 4096;
    for (int i = 0; i < 16; i++) {
        int e = base + i * 256 + tid;
        if (e < E) atomicAdd(&h[dst[e] >> 8], 1);
    }
    __syncthreads();
    for (int b = tid; b < NB; b += 256)
        if (h[b]) atomicAdd(&bucketCnt[b], h[b]);
}

// ---------------- phase 1b: scan bucket counts (1 block) -------------------
__global__ __launch_bounds__(512) void bucket_scan(const int* __restrict__ bucketCnt, int NB,
                                                   int* __restrict__ bucketOffs,
                                                   int* __restrict__ bucketCur) {
    __shared__ int sd[512];
    int t = threadIdx.x;
    int v = (t < NB) ? bucketCnt[t] : 0;
    sd[t] = v;
    __syncthreads();
    for (int off = 1; off < 512; off <<= 1) {
        int x = sd[t];
        int y = (t >= off) ? sd[t - off] : 0;
        __syncthreads();
        sd[t] = x + y;
        __syncthreads();
    }
    int excl = sd[t] - v;
    if (t <= NB) bucketOffs[t] = excl;  // bucketOffs[NB] = E sentinel
    if (t < NB) bucketCur[t] = excl;
}

// ---------------- phase 1c: partition edges + (tail blocks) weight prep ----
// LDS-restaged scatter: edges sorted by (bucket, rank) in LDS together with
// their final global address; writeout walks LDS linearly so lane addresses
// are consecutive within each bucket run (~8 edges) -> HW-coalesced stores
// (~8 transactions/wave instead of 64).
__global__ __launch_bounds__(256) void partition_wprep(
    const int* __restrict__ src, const int* __restrict__ dst, int E, int NB, int partBlocks,
    int* __restrict__ bucketCur, unsigned int* __restrict__ bucketBuf,
    const float* __restrict__ Wn1, const float* __restrict__ Ws1,
    const float* __restrict__ bn1, const float* __restrict__ bs1,
    const float* __restrict__ Wn2, const float* __restrict__ Ws2,
    const float* __restrict__ bn2, const float* __restrict__ bs2,
    unsigned short* __restrict__ Bpre, float* __restrict__ biasPre) {
    int tid = threadIdx.x;
    if ((int)blockIdx.x >= partBlocks) {
        // ---- weight prep: f32 W -> bf16 pre-swizzled fragments ----
        int wb = blockIdx.x - partBlocks;  // [0,32)
        int l = wb >> 4;
        const float* Wn = l ? Wn2 : Wn1;
        const float* Ws = l ? Ws2 : Ws1;
        int fi = (wb & 15) * 256 + tid;
        int kt = fi >> 9;
        int nt = (fi >> 6) & 7;
        int lane = fi & 63;
        int o = nt * 16 + (lane & 15);
        int k = kt * 32 + (lane >> 4) * 8;
        const float* srcp = (k < 128) ? (Wn + o * 128 + k) : (Ws + o * 128 + (k - 128));
        short8 v;
#pragma unroll
        for (int j = 0; j < 8; j++) v[j] = (short)f2bf(srcp[j]);
        ((short8*)(Bpre + (size_t)l * 32768))[fi] = v;
        if ((wb & 15) == 0 && tid < 128) {
            const float* bn = l ? bn2 : bn1;
            const float* bs = l ? bs2 : bs1;
            biasPre[l * 128 + tid] = bn[tid] + bs[tid];
        }
        return;
    }
    __shared__ int cnt[NBMAX];
    __shared__ int lofs[NBMAX];
    __shared__ int gbase[NBMAX];
    __shared__ int sc[256];
    __shared__ unsigned int ldsE[4096];
    __shared__ int ldsA[4096];
    for (int b = tid; b < NBMAX; b += 256) cnt[b] = 0;
    __syncthreads();
    int eb = blockIdx.x * 4096;
    int tot = min(4096, E - eb);
    unsigned int pk[16];
    int bk[16], rk[16];
    for (int i = 0; i < 16; i++) {
        int e = eb + i * 256 + tid;
        if (e < E) {
            int d = dst[e];
            bk[i] = d >> 8;
            pk[i] = (unsigned)src[e] | ((unsigned)(d & 255) << 24);
            rk[i] = atomicAdd(&cnt[bk[i]], 1);
        } else {
            bk[i] = -1;
        }
    }
    __syncthreads();
    // exclusive scan over cnt[0..511], 2 buckets/thread
    int b0 = 2 * tid, b1 = 2 * tid + 1;
    int c0 = cnt[b0], c1 = cnt[b1];
    int ts = c0 + c1;
    sc[tid] = ts;
    __syncthreads();
    for (int off = 1; off < 256; off <<= 1) {
        int x = sc[tid];
        int y = (tid >= off) ? sc[tid - off] : 0;
        __syncthreads();
        sc[tid] = x + y;
        __syncthreads();
    }
    int excl = sc[tid] - ts;
    lofs[b0] = excl;
    lofs[b1] = excl + c0;
    gbase[b0] = c0 ? atomicAdd(&bucketCur[b0], c0) : 0;
    gbase[b1] = c1 ? atomicAdd(&bucketCur[b1], c1) : 0;
    __syncthreads();
    for (int i = 0; i < 16; i++) {
        if (bk[i] >= 0) {
            int p = lofs[bk[i]] + rk[i];
            ldsE[p] = pk[i];
            ldsA[p] = gbase[bk[i]] + rk[i];
        }
    }
    __syncthreads();
    for (int i = tid; i < tot; i += 256) bucketBuf[ldsA[i]] = ldsE[i];
}

// ---------------- phase 2: per-bucket CSR build + (tail blocks) x->bf16 ----
// LDS-restaged scatter: srcs sorted by dst rank into LDS, then streamed out
// as sortedSrc[bo+i] -> perfectly coalesced global writes.
__global__ __launch_bounds__(256) void csrbuild_cvt(
    const unsigned int* __restrict__ bucketBuf, const int* __restrict__ bucketOffs,
    int N, int NB, int* __restrict__ deg, int* __restrict__ offs, int* __restrict__ sortedSrc,
    const float* __restrict__ xin, unsigned int* __restrict__ xb, int n2) {
    int tid = threadIdx.x;
    if ((int)blockIdx.x >= NB) {
        // ---- cvt: f32 [N,128] -> packed bf16 u32 [N,64], 8 u32/thread ----
        int cb = blockIdx.x - NB;
        int base = cb * 2048 + tid;
        if (xb) {
#pragma unroll
            for (int i = 0; i < 8; i++) {
                int t = base + i * 256;
                if (t < n2) {
                    float2 v = ((const float2*)xin)[t];
                    xb[t] = (unsigned)f2bf(v.x) | ((unsigned)f2bf(v.y) << 16);
                }
            }
        }
        return;
    }
    __shared__ int h[256];
    __shared__ int sc[256];
    __shared__ int cur[256];
    __shared__ unsigned int ldsE[6144];
    int b = blockIdx.x;
    int n0 = b << 8;
    int bo = bucketOffs[b];
    int cnt = bucketOffs[b + 1] - bo;
    h[tid] = 0;
    __syncthreads();
    for (int i = tid; i < cnt; i += 256) atomicAdd(&h[bucketBuf[bo + i] >> 24], 1);
    __syncthreads();
    int v = h[tid];
    sc[tid] = v;
    __syncthreads();
    for (int off = 1; off < 256; off <<= 1) {
        int x = sc[tid];
        int y = (tid >= off) ? sc[tid - off] : 0;
        __syncthreads();
        sc[tid] = x + y;
        __syncthreads();
    }
    int excl = sc[tid] - v;
    cur[tid] = excl;  // LOCAL rank cursor
    int n = n0 + tid;
    if (n < N) {
        deg[n] = v;
        offs[n] = bo + excl;
    }
    __syncthreads();
    if (cnt <= 6144) {
        for (int i = tid; i < cnt; i += 256) {
            unsigned int pv = bucketBuf[bo + i];
            int pos = atomicAdd(&cur[pv >> 24], 1);
            ldsE[pos] = pv & 0xFFFFFFu;
        }
        __syncthreads();
        for (int i = tid; i < cnt; i += 256) sortedSrc[bo + i] = (int)ldsE[i];
    } else {  // overflow fallback (astronomically rare): direct scatter
        for (int i = tid; i < cnt; i += 256) {
            unsigned int pv = bucketBuf[bo + i];
            int pos = atomicAdd(&cur[pv >> 24], 1);
            sortedSrc[bo + pos] = (int)(pv & 0xFFFFFFu);
        }
    }
}

// ---------------- mean agg, bf16 source (wave/node, 16-deep, SGPR bases) ----
__global__ __launch_bounds__(256) void agg_bf16_kernel(
    const unsigned int* __restrict__ srcFeats,
    const int* __restrict__ deg, const int* __restrict__ offs,
    const int* __restrict__ sortedSrc,
    unsigned int* __restrict__ dst, int Nn) {
    int wave = threadIdx.x >> 6, lane = threadIdx.x & 63;
    int n = blockIdx.x * 4 + wave;
    if (n >= Nn) return;
    int d = deg[n], st = offs[n];
    float a0 = 0.f, a1 = 0.f;
    int j = 0;
    for (; j + 16 <= d; j += 16) {
        unsigned int uu[16];
#pragma unroll
        for (int u = 0; u < 16; u++) {
            int s = __builtin_amdgcn_readfirstlane(sortedSrc[st + j + u]);
            uu[u] = (srcFeats + (size_t)s * 64)[lane];
        }
#pragma unroll
        for (int u = 0; u < 16; u++) {
            a0 += __uint_as_float(uu[u] << 16);
            a1 += __uint_as_float(uu[u] & 0xFFFF0000u);
        }
    }
    for (; j + 8 <= d; j += 8) {
        unsigned int uu[8];
#pragma unroll
        for (int u = 0; u < 8; u++) {
            int s = __builtin_amdgcn_readfirstlane(sortedSrc[st + j + u]);
            uu[u] = (srcFeats + (size_t)s * 64)[lane];
        }
#pragma unroll
        for (int u = 0; u < 8; u++) {
            a0 += __uint_as_float(uu[u] << 16);
            a1 += __uint_as_float(uu[u] & 0xFFFF0000u);
        }
    }
    for (; j < d; j++) {
        int s = __builtin_amdgcn_readfirstlane(sortedSrc[st + j]);
        unsigned int u = (srcFeats + (size_t)s * 64)[lane];
        a0 += __uint_as_float(u << 16);
        a1 += __uint_as_float(u & 0xFFFF0000u);
    }
    float inv = 1.0f / (float)max(d, 1);
    dst[(size_t)n * 64 + lane] = (unsigned)f2bf(a0 * inv) | ((unsigned)f2bf(a1 * inv) << 16);
}

// ---------------- mean agg, f32 source (fallback layout B) ------------------
__global__ __launch_bounds__(256) void agg_f32_kernel(
    const float* __restrict__ srcFeats,
    const int* __restrict__ deg, const int* __restrict__ offs,
    const int* __restrict__ sortedSrc,
    unsigned int* __restrict__ dst, int Nn) {
    int wave = threadIdx.x >> 6, lane = threadIdx.x & 63;
    int n = blockIdx.x * 4 + wave;
    if (n >= Nn) return;
    int d = deg[n], st = offs[n];
    float a0 = 0.f, a1 = 0.f;
    int j = 0;
    for (; j + 8 <= d; j += 8) {
        float2 v[8];
#pragma unroll
        for (int u = 0; u < 8; u++) {
            int s = __builtin_amdgcn_readfirstlane(sortedSrc[st + j + u]);
            v[u] = ((const float2*)(srcFeats + (size_t)s * 128))[lane];
        }
#pragma unroll
        for (int u = 0; u < 8; u++) {
            a0 += v[u].x;
            a1 += v[u].y;
        }
    }
    for (; j < d; j++) {
        int s = __builtin_amdgcn_readfirstlane(sortedSrc[st + j]);
        float2 v = ((const float2*)(srcFeats + (size_t)s * 128))[lane];
        a0 += v.x;
        a1 += v.y;
    }
    float inv = 1.0f / (float)max(d, 1);
    dst[(size_t)n * 64 + lane] = (unsigned)f2bf(a0 * inv) | ((unsigned)f2bf(a1 * inv) << 16);
}

// ---------------- fused GEMM: out = act([Aagg|Aself] @ B^T + bias) ---------
// Aagg: [N,128] bf16. Aself: bf16 (selfF32=0) or f32 (selfF32=1).
// Bpre: 64KB pre-swizzled bf16 fragments; biasPre: 128 f32 (bn+bs).
// Out: bf16 (outBf16=1) or f32. MFMA 16x16x32 bf16; 4 waves, 128 rows/block.
// Out may alias Aself (fallback layer 2): each wave reads only its own 32
// rows before writing them -> safe. (No __restrict__ on Aself/Out.)
__global__ __launch_bounds__(256) void gemm_kernel(
    const unsigned short* __restrict__ Aagg, const void* Aself,
    const unsigned short* __restrict__ Bpre, const float* __restrict__ biasPre,
    void* Out, int relu, int selfF32, int outBf16, int Nrows) {
    __shared__ unsigned short ldsB[8 * 8 * 64 * 8];  // 64 KB
    __shared__ float biasS[128];
    int tid = threadIdx.x;

    // Pure coalesced copy: Bpre is already bf16 in fragment order.
#pragma unroll
    for (int i = 0; i < 16; i++) {
        int fi = tid + 256 * i;
        ((short8*)ldsB)[fi] = ((const short8*)Bpre)[fi];
    }
    if (tid < 128) biasS[tid] = biasPre[tid];
    __syncthreads();

    int wave = tid >> 6, lane = tid & 63;
    int quad = lane >> 4, mr = lane & 15;
    int rowBase = blockIdx.x * 128 + wave * 32;

    float4_ acc[2][8];
    float4_ z = {0.f, 0.f, 0.f, 0.f};
    for (int mt = 0; mt < 2; mt++)
        for (int nt = 0; nt < 8; nt++) acc[mt][nt] = z;

    for (int kt = 0; kt < 8; kt++) {
        int kk = (kt & 3) * 32 + quad * 8;
        short8 a[2];
        for (int mt = 0; mt < 2; mt++) {
            int row = rowBase + mt * 16 + mr;
            if (row >= Nrows) row = Nrows - 1;  // in-bounds; result discarded
            if (kt < 4) {
                a[mt] = *(const short8*)(Aagg + (size_t)row * 128 + kk);
            } else if (selfF32) {
                const float* p = (const float*)Aself + (size_t)row * 128 + kk;
                float4_ f0 = *(const float4_*)p;
                float4_ f1 = *(const float4_*)(p + 4);
                short8 t;
#pragma unroll
                for (int j = 0; j < 4; j++) {
                    t[j] = (short)f2bf(f0[j]);
                    t[4 + j] = (short)f2bf(f1[j]);
                }
                a[mt] = t;
            } else {
                a[mt] = *(const short8*)((const unsigned short*)Aself + (size_t)row * 128 + kk);
            }
        }
        for (int nt = 0; nt < 8; nt++) {
            short8 b = *(const short8*)(ldsB + ((size_t)(kt * 8 + nt) * 64 + lane) * 8);
            acc[0][nt] = __builtin_amdgcn_mfma_f32_16x16x32_bf16(a[0], b, acc[0][nt], 0, 0, 0);
            acc[1][nt] = __builtin_amdgcn_mfma_f32_16x16x32_bf16(a[1], b, acc[1][nt], 0, 0, 0);
        }
    }

    // C/D layout: col = lane&15, row = (lane>>4)*4 + reg
    for (int mt = 0; mt < 2; mt++) {
        for (int nt = 0; nt < 8; nt++) {
            int col = nt * 16 + mr;
            float bv = biasS[col];
            for (int r = 0; r < 4; r++) {
                int row = rowBase + mt * 16 + quad * 4 + r;
                if (row < Nrows) {
                    float v = acc[mt][nt][r] + bv;
                    if (relu) v = fmaxf(v, 0.f);
                    if (outBf16)
                        ((unsigned short*)Out)[(size_t)row * 128 + col] = f2bf(v);
                    else
                        ((float*)Out)[(size_t)row * 128 + col] = v;
                }
            }
        }
    }
}

extern "C" void kernel_launch(void* const* d_in, const int* in_sizes, int n_in,
                              void* d_out, int out_size, void* d_ws, size_t ws_size,
                              hipStream_t stream) {
    const float* x = (const float*)d_in[0];
    const int* ei = (const int*)d_in[1];
    const float* Wn1 = (const float*)d_in[2];
    const float* bn1 = (const float*)d_in[3];
    const float* Ws1 = (const float*)d_in[4];
    const float* bs1 = (const float*)d_in[5];
    const float* Wn2 = (const float*)d_in[6];
    const float* bn2 = (const float*)d_in[7];
    const float* Ws2 = (const float*)d_in[8];
    const float* bs2 = (const float*)d_in[9];

    const int N = in_sizes[0] / 128;
    const int E = in_sizes[1] / 2;
    const int* srcI = ei;
    const int* dstI = ei + E;
    const int NB = (N + 255) >> 8;  // <= NBMAX for N <= 131072

    char* ws = (char*)d_ws;
    size_t off = 0;
    auto alloc = [&](size_t bytes) -> void* {
        void* p = ws + off;
        off += (bytes + 255) & ~(size_t)255;
        return p;
    };
    int* deg = (int*)alloc((size_t)N * 4);
    int* offs = (int*)alloc((size_t)N * 4);
    int* bucketCnt = (int*)alloc((NBMAX + 1) * 4);
    int* bucketOffs = (int*)alloc((NBMAX + 1) * 4);
    int* bucketCur = (int*)alloc((NBMAX + 1) * 4);
    unsigned short* Bpre = (unsigned short*)alloc(2 * 32768 * 2);
    float* biasPre = (float*)alloc(2 * 128 * 4);
    int* sortedSrc = (int*)alloc((size_t)E * 4);
    unsigned short* Aagg = (unsigned short*)alloc((size_t)N * 128 * 2);
    size_t baseNeed = off;
    size_t bf16Buf = ((size_t)N * 128 * 2 + 255) & ~(size_t)255;
    bool bigWs = (ws_size >= baseNeed + 2 * bf16Buf);
    unsigned int* xb = nullptr;
    unsigned short* h1b = nullptr;
    if (bigWs) {
        xb = (unsigned int*)alloc((size_t)N * 128 * 2);
        h1b = (unsigned short*)alloc((size_t)N * 128 * 2);
    }
    // bucketBuf (E u32, 6.4 MB) aliases Aagg (dead until agg1)
    unsigned int* bucketBuf = (unsigned int*)Aagg;

    // ---- CSR build + overlapped wprep/cvt ----
    int ebBlocks = (E + 4095) / 4096;
    int n2 = N * 64;
    int cvtBlocks = bigWs ? (n2 + 2047) / 2048 : 0;
    hipMemsetAsync(bucketCnt, 0, (size_t)NB * 4, stream);
    bucket_count<<<ebBlocks, 256, 0, stream>>>(dstI, E, NB, bucketCnt);
    bucket_scan<<<1, 512, 0, stream>>>(bucketCnt, NB, bucketOffs, bucketCur);
    partition_wprep<<<ebBlocks + 32, 256, 0, stream>>>(
        srcI, dstI, E, NB, ebBlocks, bucketCur, bucketBuf,
        Wn1, Ws1, bn1, bs1, Wn2, Ws2, bn2, bs2, Bpre, biasPre);
    csrbuild_cvt<<<NB + cvtBlocks, 256, 0, stream>>>(bucketBuf, bucketOffs, N, NB, deg, offs,
                                                     sortedSrc, x, xb, n2);

    int aggBlocks = (N + 3) / 4;
    int gemmBlocks = (N + 127) / 128;

    if (bigWs) {
        // Layout A: all gathers bf16 (256 B/row)
        agg_bf16_kernel<<<aggBlocks, 256, 0, stream>>>(xb, deg, offs, sortedSrc,
                                                       (unsigned int*)Aagg, N);
        gemm_kernel<<<gemmBlocks, 256, 0, stream>>>(Aagg, xb, Bpre, biasPre, h1b, 1, 0, 1, N);
        agg_bf16_kernel<<<aggBlocks, 256, 0, stream>>>((const unsigned int*)h1b, deg, offs,
                                                       sortedSrc, (unsigned int*)Aagg, N);
        gemm_kernel<<<gemmBlocks, 256, 0, stream>>>(Aagg, h1b, Bpre + 32768, biasPre + 128,
                                                    d_out, 0, 0, 0, N);
    } else {
        // Layout B: f32 gathers, h1 f32 staged in d_out
        float* h1 = (float*)d_out;
        agg_f32_kernel<<<aggBlocks, 256, 0, stream>>>(x, deg, offs, sortedSrc,
                                                      (unsigned int*)Aagg, N);
        gemm_kernel<<<gemmBlocks, 256, 0, stream>>>(Aagg, x, Bpre, biasPre, h1, 1, 1, 0, N);
        agg_f32_kernel<<<aggBlocks, 256, 0, stream>>>(h1, deg, offs, sortedSrc,
                                                      (unsigned int*)Aagg, N);
        gemm_kernel<<<gemmBlocks, 256, 0, stream>>>(Aagg, h1, Bpre + 32768, biasPre + 128,
                                                    d_out, 0, 1, 0, N);
    }
}

// Round 4
// 345.811 us; speedup vs baseline: 2.2645x; 1.0462x over previous
//
#include <hip/hip_runtime.h>
#include <hip/hip_bf16.h>

// GraphSAGE 2-layer, N=100000, E=1.6M, D=128. f32 I/O, bf16 MFMA compute.
//
// R12: atomic-free CSR bucketing. R11 post-mortem: LDS-restaged scatter
// stores cost +11us -> scatter stores are NOT the bottleneck; reverted to
// R8 direct scatters. New theory: bucket_count/partition each fire ~150K
// global atomics onto the same ~13 cache lines (391-int arrays) -> ~20us
// serialization each at the owning TCC channels. Fix: deterministic
// 2-level histogram. bucket_count writes private hist[blk][NB] (coalesced);
// blk_scan (block=bucket) scans across blocks -> per-(blk,bucket) exclusive
// base + bucketCnt; bucket_scan scans totals. partition computes write
// bases by pure loads. Zero global atomics in the whole CSR pipeline.
// agg (69.4us) is at the measured line-fill cap (2 fills/edge @ ~0.073
// fills/cy/CU); gemms near streaming roofline. Those stay R8-identical.
//
// Pipeline (9 dispatches): bucket_count -> blk_scan -> bucket_scan ->
//   partition+wprep -> csr_build+cvt -> agg1 -> gemm1(relu->h1b) -> agg2 ->
//   gemm2 -> d_out f32.  Fallback layout B (small ws): f32 gathers, h1 f32
//   staged in d_out.

typedef __attribute__((ext_vector_type(8))) short short8;
typedef __attribute__((ext_vector_type(4))) float float4_;

#define NBMAX 512  // max buckets (256 nodes each) -> N <= 131072

__device__ __forceinline__ unsigned short f2bf(float f) {
    unsigned int u = __float_as_uint(f);
    unsigned int r = (u + 0x7FFFu + ((u >> 16) & 1u)) >> 16;
    return (unsigned short)r;
}

// ---------------- phase 1a: per-block bucket histogram ---------------------
// Writes private histogram hist[blk][NB] (coalesced). No global atomics.
__global__ __launch_bounds__(256) void bucket_count(const int* __restrict__ dst, int E, int NB,
                                                    int* __restrict__ hist) {
    __shared__ int h[NBMAX];
    int tid = threadIdx.x;
    for (int b = tid; b < NB; b += 256) h[b] = 0;
    __syncthreads();
    int base = blockIdx.x * 4096;
    for (int i = 0; i < 16; i++) {
        int e = base + i * 256 + tid;
        if (e < E) atomicAdd(&h[dst[e] >> 8], 1);
    }
    __syncthreads();
    int* out = hist + (size_t)blockIdx.x * NB;
    for (int b = tid; b < NB; b += 256) out[b] = h[b];
}

// ---------------- phase 1b-1: cross-block scan per bucket ------------------
// Block b scans hist[0..nblk)[b] -> baseT[blk][b] (exclusive) + bucketCnt[b].
__global__ __launch_bounds__(256) void blk_scan(const int* __restrict__ hist, int nblk, int NB,
                                                int* __restrict__ baseT,
                                                int* __restrict__ bucketCnt) {
    __shared__ int sd[256];
    __shared__ int carryS;
    int b = blockIdx.x, tid = threadIdx.x;
    if (tid == 0) carryS = 0;
    __syncthreads();
    for (int c0 = 0; c0 < nblk; c0 += 256) {
        int i = c0 + tid;
        int v = (i < nblk) ? hist[(size_t)i * NB + b] : 0;
        sd[tid] = v;
        __syncthreads();
        for (int off = 1; off < 256; off <<= 1) {
            int x = sd[tid];
            int y = (tid >= off) ? sd[tid - off] : 0;
            __syncthreads();
            sd[tid] = x + y;
            __syncthreads();
        }
        int carry = carryS;
        if (i < nblk) baseT[(size_t)i * NB + b] = carry + sd[tid] - v;
        __syncthreads();
        if (tid == 255) carryS = carry + sd[255];
        __syncthreads();
    }
    if (tid == 0) bucketCnt[b] = carryS;
}

// ---------------- phase 1b-2: scan bucket totals (1 block) -----------------
__global__ __launch_bounds__(512) void bucket_scan(const int* __restrict__ bucketCnt, int NB,
                                                   int* __restrict__ bucketOffs) {
    __shared__ int sd[512];
    int t = threadIdx.x;
    int v = (t < NB) ? bucketCnt[t] : 0;
    sd[t] = v;
    __syncthreads();
    for (int off = 1; off < 512; off <<= 1) {
        int x = sd[t];
        int y = (t >= off) ? sd[t - off] : 0;
        __syncthreads();
        sd[t] = x + y;
        __syncthreads();
    }
    int excl = sd[t] - v;
    if (t <= NB) bucketOffs[t] = excl;  // bucketOffs[NB] = E sentinel
}

// ---------------- phase 1c: partition edges + (tail blocks) weight prep ----
// Write base per (block,bucket) from baseT (pure loads, no atomics);
// direct scatter (R8 style — proven faster than LDS restage, R11).
__global__ __launch_bounds__(256) void partition_wprep(
    const int* __restrict__ src, const int* __restrict__ dst, int E, int NB, int partBlocks,
    const int* __restrict__ bucketOffs, const int* __restrict__ baseT,
    unsigned int* __restrict__ bucketBuf,
    const float* __restrict__ Wn1, const float* __restrict__ Ws1,
    const float* __restrict__ bn1, const float* __restrict__ bs1,
    const float* __restrict__ Wn2, const float* __restrict__ Ws2,
    const float* __restrict__ bn2, const float* __restrict__ bs2,
    unsigned short* __restrict__ Bpre, float* __restrict__ biasPre) {
    int tid = threadIdx.x;
    if ((int)blockIdx.x >= partBlocks) {
        // ---- weight prep: f32 W -> bf16 pre-swizzled fragments ----
        int wb = blockIdx.x - partBlocks;  // [0,32)
        int l = wb >> 4;
        const float* Wn = l ? Wn2 : Wn1;
        const float* Ws = l ? Ws2 : Ws1;
        int fi = (wb & 15) * 256 + tid;
        int kt = fi >> 9;
        int nt = (fi >> 6) & 7;
        int lane = fi & 63;
        int o = nt * 16 + (lane & 15);
        int k = kt * 32 + (lane >> 4) * 8;
        const float* srcp = (k < 128) ? (Wn + o * 128 + k) : (Ws + o * 128 + (k - 128));
        short8 v;
#pragma unroll
        for (int j = 0; j < 8; j++) v[j] = (short)f2bf(srcp[j]);
        ((short8*)(Bpre + (size_t)l * 32768))[fi] = v;
        if ((wb & 15) == 0 && tid < 128) {
            const float* bn = l ? bn2 : bn1;
            const float* bs = l ? bs2 : bs1;
            biasPre[l * 128 + tid] = bn[tid] + bs[tid];
        }
        return;
    }
    __shared__ int cnt[NBMAX];
    __shared__ int gb[NBMAX];
    for (int b = tid; b < NB; b += 256) {
        cnt[b] = 0;
        gb[b] = bucketOffs[b] + baseT[(size_t)blockIdx.x * NB + b];
    }
    __syncthreads();
    int eb = blockIdx.x * 4096;
    unsigned int pk[16];
    int bk[16], rk[16];
    for (int i = 0; i < 16; i++) {
        int e = eb + i * 256 + tid;
        if (e < E) {
            int d = dst[e];
            bk[i] = d >> 8;
            pk[i] = (unsigned)src[e] | ((unsigned)(d & 255) << 24);
            rk[i] = atomicAdd(&cnt[bk[i]], 1);
        } else {
            bk[i] = -1;
        }
    }
    __syncthreads();
    for (int i = 0; i < 16; i++)
        if (bk[i] >= 0) bucketBuf[gb[bk[i]] + rk[i]] = pk[i];
}

// ---------------- phase 2: per-bucket CSR build + (tail blocks) x->bf16 ----
__global__ __launch_bounds__(256) void csrbuild_cvt(
    const unsigned int* __restrict__ bucketBuf, const int* __restrict__ bucketOffs,
    int N, int NB, int* __restrict__ deg, int* __restrict__ offs, int* __restrict__ sortedSrc,
    const float* __restrict__ xin, unsigned int* __restrict__ xb, int n2) {
    int tid = threadIdx.x;
    if ((int)blockIdx.x >= NB) {
        // ---- cvt: f32 [N,128] -> packed bf16 u32 [N,64], 8 u32/thread ----
        int cb = blockIdx.x - NB;
        int base = cb * 2048 + tid;
        if (xb) {
#pragma unroll
            for (int i = 0; i < 8; i++) {
                int t = base + i * 256;
                if (t < n2) {
                    float2 v = ((const float2*)xin)[t];
                    xb[t] = (unsigned)f2bf(v.x) | ((unsigned)f2bf(v.y) << 16);
                }
            }
        }
        return;
    }
    __shared__ int h[256];
    __shared__ int sc[256];
    __shared__ int cur[256];
    int b = blockIdx.x;
    int n0 = b << 8;
    int bo = bucketOffs[b];
    int cnt = bucketOffs[b + 1] - bo;
    h[tid] = 0;
    __syncthreads();
    for (int i = tid; i < cnt; i += 256) atomicAdd(&h[bucketBuf[bo + i] >> 24], 1);
    __syncthreads();
    int v = h[tid];
    sc[tid] = v;
    __syncthreads();
    for (int off = 1; off < 256; off <<= 1) {
        int x = sc[tid];
        int y = (tid >= off) ? sc[tid - off] : 0;
        __syncthreads();
        sc[tid] = x + y;
        __syncthreads();
    }
    int excl = sc[tid] - v;
    cur[tid] = bo + excl;
    int n = n0 + tid;
    if (n < N) {
        deg[n] = v;
        offs[n] = bo + excl;
    }
    __syncthreads();
    for (int i = tid; i < cnt; i += 256) {
        unsigned int pv = bucketBuf[bo + i];
        int pos = atomicAdd(&cur[pv >> 24], 1);
        sortedSrc[pos] = (int)(pv & 0xFFFFFFu);
    }
}

// ---------------- mean agg, bf16 source (wave/node, 16-deep, SGPR bases) ----
__global__ __launch_bounds__(256) void agg_bf16_kernel(
    const unsigned int* __restrict__ srcFeats,
    const int* __restrict__ deg, const int* __restrict__ offs,
    const int* __restrict__ sortedSrc,
    unsigned int* __restrict__ dst, int Nn) {
    int wave = threadIdx.x >> 6, lane = threadIdx.x & 63;
    int n = blockIdx.x * 4 + wave;
    if (n >= Nn) return;
    int d = deg[n], st = offs[n];
    float a0 = 0.f, a1 = 0.f;
    int j = 0;
    for (; j + 16 <= d; j += 16) {
        unsigned int uu[16];
#pragma unroll
        for (int u = 0; u < 16; u++) {
            int s = __builtin_amdgcn_readfirstlane(sortedSrc[st + j + u]);
            uu[u] = (srcFeats + (size_t)s * 64)[lane];
        }
#pragma unroll
        for (int u = 0; u < 16; u++) {
            a0 += __uint_as_float(uu[u] << 16);
            a1 += __uint_as_float(uu[u] & 0xFFFF0000u);
        }
    }
    for (; j + 8 <= d; j += 8) {
        unsigned int uu[8];
#pragma unroll
        for (int u = 0; u < 8; u++) {
            int s = __builtin_amdgcn_readfirstlane(sortedSrc[st + j + u]);
            uu[u] = (srcFeats + (size_t)s * 64)[lane];
        }
#pragma unroll
        for (int u = 0; u < 8; u++) {
            a0 += __uint_as_float(uu[u] << 16);
            a1 += __uint_as_float(uu[u] & 0xFFFF0000u);
        }
    }
    for (; j < d; j++) {
        int s = __builtin_amdgcn_readfirstlane(sortedSrc[st + j]);
        unsigned int u = (srcFeats + (size_t)s * 64)[lane];
        a0 += __uint_as_float(u << 16);
        a1 += __uint_as_float(u & 0xFFFF0000u);
    }
    float inv = 1.0f / (float)max(d, 1);
    dst[(size_t)n * 64 + lane] = (unsigned)f2bf(a0 * inv) | ((unsigned)f2bf(a1 * inv) << 16);
}

// ---------------- mean agg, f32 source (fallback layout B) ------------------
__global__ __launch_bounds__(256) void agg_f32_kernel(
    const float* __restrict__ srcFeats,
    const int* __restrict__ deg, const int* __restrict__ offs,
    const int* __restrict__ sortedSrc,
    unsigned int* __restrict__ dst, int Nn) {
    int wave = threadIdx.x >> 6, lane = threadIdx.x & 63;
    int n = blockIdx.x * 4 + wave;
    if (n >= Nn) return;
    int d = deg[n], st = offs[n];
    float a0 = 0.f, a1 = 0.f;
    int j = 0;
    for (; j + 8 <= d; j += 8) {
        float2 v[8];
#pragma unroll
        for (int u = 0; u < 8; u++) {
            int s = __builtin_amdgcn_readfirstlane(sortedSrc[st + j + u]);
            v[u] = ((const float2*)(srcFeats + (size_t)s * 128))[lane];
        }
#pragma unroll
        for (int u = 0; u < 8; u++) {
            a0 += v[u].x;
            a1 += v[u].y;
        }
    }
    for (; j < d; j++) {
        int s = __builtin_amdgcn_readfirstlane(sortedSrc[st + j]);
        float2 v = ((const float2*)(srcFeats + (size_t)s * 128))[lane];
        a0 += v.x;
        a1 += v.y;
    }
    float inv = 1.0f / (float)max(d, 1);
    dst[(size_t)n * 64 + lane] = (unsigned)f2bf(a0 * inv) | ((unsigned)f2bf(a1 * inv) << 16);
}

// ---------------- fused GEMM: out = act([Aagg|Aself] @ B^T + bias) ---------
// Aagg: [N,128] bf16. Aself: bf16 (selfF32=0) or f32 (selfF32=1).
// Bpre: 64KB pre-swizzled bf16 fragments; biasPre: 128 f32 (bn+bs).
// Out: bf16 (outBf16=1) or f32. MFMA 16x16x32 bf16; 4 waves, 128 rows/block.
// Out may alias Aself (fallback layer 2): each wave reads only its own 32
// rows before writing them -> safe. (No __restrict__ on Aself/Out.)
__global__ __launch_bounds__(256) void gemm_kernel(
    const unsigned short* __restrict__ Aagg, const void* Aself,
    const unsigned short* __restrict__ Bpre, const float* __restrict__ biasPre,
    void* Out, int relu, int selfF32, int outBf16, int Nrows) {
    __shared__ unsigned short ldsB[8 * 8 * 64 * 8];  // 64 KB
    __shared__ float biasS[128];
    int tid = threadIdx.x;

    // Pure coalesced copy: Bpre is already bf16 in fragment order.
#pragma unroll
    for (int i = 0; i < 16; i++) {
        int fi = tid + 256 * i;
        ((short8*)ldsB)[fi] = ((const short8*)Bpre)[fi];
    }
    if (tid < 128) biasS[tid] = biasPre[tid];
    __syncthreads();

    int wave = tid >> 6, lane = tid & 63;
    int quad = lane >> 4, mr = lane & 15;
    int rowBase = blockIdx.x * 128 + wave * 32;

    float4_ acc[2][8];
    float4_ z = {0.f, 0.f, 0.f, 0.f};
    for (int mt = 0; mt < 2; mt++)
        for (int nt = 0; nt < 8; nt++) acc[mt][nt] = z;

    for (int kt = 0; kt < 8; kt++) {
        int kk = (kt & 3) * 32 + quad * 8;
        short8 a[2];
        for (int mt = 0; mt < 2; mt++) {
            int row = rowBase + mt * 16 + mr;
            if (row >= Nrows) row = Nrows - 1;  // in-bounds; result discarded
            if (kt < 4) {
                a[mt] = *(const short8*)(Aagg + (size_t)row * 128 + kk);
            } else if (selfF32) {
                const float* p = (const float*)Aself + (size_t)row * 128 + kk;
                float4_ f0 = *(const float4_*)p;
                float4_ f1 = *(const float4_*)(p + 4);
                short8 t;
#pragma unroll
                for (int j = 0; j < 4; j++) {
                    t[j] = (short)f2bf(f0[j]);
                    t[4 + j] = (short)f2bf(f1[j]);
                }
                a[mt] = t;
            } else {
                a[mt] = *(const short8*)((const unsigned short*)Aself + (size_t)row * 128 + kk);
            }
        }
        for (int nt = 0; nt < 8; nt++) {
            short8 b = *(const short8*)(ldsB + ((size_t)(kt * 8 + nt) * 64 + lane) * 8);
            acc[0][nt] = __builtin_amdgcn_mfma_f32_16x16x32_bf16(a[0], b, acc[0][nt], 0, 0, 0);
            acc[1][nt] = __builtin_amdgcn_mfma_f32_16x16x32_bf16(a[1], b, acc[1][nt], 0, 0, 0);
        }
    }

    // C/D layout: col = lane&15, row = (lane>>4)*4 + reg
    for (int mt = 0; mt < 2; mt++) {
        for (int nt = 0; nt < 8; nt++) {
            int col = nt * 16 + mr;
            float bv = biasS[col];
            for (int r = 0; r < 4; r++) {
                int row = rowBase + mt * 16 + quad * 4 + r;
                if (row < Nrows) {
                    float v = acc[mt][nt][r] + bv;
                    if (relu) v = fmaxf(v, 0.f);
                    if (outBf16)
                        ((unsigned short*)Out)[(size_t)row * 128 + col] = f2bf(v);
                    else
                        ((float*)Out)[(size_t)row * 128 + col] = v;
                }
            }
        }
    }
}

extern "C" void kernel_launch(void* const* d_in, const int* in_sizes, int n_in,
                              void* d_out, int out_size, void* d_ws, size_t ws_size,
                              hipStream_t stream) {
    const float* x = (const float*)d_in[0];
    const int* ei = (const int*)d_in[1];
    const float* Wn1 = (const float*)d_in[2];
    const float* bn1 = (const float*)d_in[3];
    const float* Ws1 = (const float*)d_in[4];
    const float* bs1 = (const float*)d_in[5];
    const float* Wn2 = (const float*)d_in[6];
    const float* bn2 = (const float*)d_in[7];
    const float* Ws2 = (const float*)d_in[8];
    const float* bs2 = (const float*)d_in[9];

    const int N = in_sizes[0] / 128;
    const int E = in_sizes[1] / 2;
    const int* srcI = ei;
    const int* dstI = ei + E;
    const int NB = (N + 255) >> 8;  // <= NBMAX for N <= 131072
    const int ebBlocks = (E + 4095) / 4096;

    char* ws = (char*)d_ws;
    size_t off = 0;
    auto alloc = [&](size_t bytes) -> void* {
        void* p = ws + off;
        off += (bytes + 255) & ~(size_t)255;
        return p;
    };
    int* deg = (int*)alloc((size_t)N * 4);
    int* offs = (int*)alloc((size_t)N * 4);
    int* bucketCnt = (int*)alloc((NBMAX + 1) * 4);
    int* bucketOffs = (int*)alloc((NBMAX + 1) * 4);
    int* hist = (int*)alloc((size_t)ebBlocks * NB * 4);
    int* baseT = (int*)alloc((size_t)ebBlocks * NB * 4);
    unsigned short* Bpre = (unsigned short*)alloc(2 * 32768 * 2);
    float* biasPre = (float*)alloc(2 * 128 * 4);
    int* sortedSrc = (int*)alloc((size_t)E * 4);
    unsigned short* Aagg = (unsigned short*)alloc((size_t)N * 128 * 2);
    size_t baseNeed = off;
    size_t bf16Buf = ((size_t)N * 128 * 2 + 255) & ~(size_t)255;
    bool bigWs = (ws_size >= baseNeed + 2 * bf16Buf);
    unsigned int* xb = nullptr;
    unsigned short* h1b = nullptr;
    if (bigWs) {
        xb = (unsigned int*)alloc((size_t)N * 128 * 2);
        h1b = (unsigned short*)alloc((size_t)N * 128 * 2);
    }
    // bucketBuf (E u32, 6.4 MB) aliases Aagg (dead until agg1)
    unsigned int* bucketBuf = (unsigned int*)Aagg;

    // ---- CSR build (atomic-free bucketing) + overlapped wprep/cvt ----
    int n2 = N * 64;
    int cvtBlocks = bigWs ? (n2 + 2047) / 2048 : 0;
    bucket_count<<<ebBlocks, 256, 0, stream>>>(dstI, E, NB, hist);
    blk_scan<<<NB, 256, 0, stream>>>(hist, ebBlocks, NB, baseT, bucketCnt);
    bucket_scan<<<1, 512, 0, stream>>>(bucketCnt, NB, bucketOffs);
    partition_wprep<<<ebBlocks + 32, 256, 0, stream>>>(
        srcI, dstI, E, NB, ebBlocks, bucketOffs, baseT, bucketBuf,
        Wn1, Ws1, bn1, bs1, Wn2, Ws2, bn2, bs2, Bpre, biasPre);
    csrbuild_cvt<<<NB + cvtBlocks, 256, 0, stream>>>(bucketBuf, bucketOffs, N, NB, deg, offs,
                                                     sortedSrc, x, xb, n2);

    int aggBlocks = (N + 3) / 4;
    int gemmBlocks = (N + 127) / 128;

    if (bigWs) {
        // Layout A: all gathers bf16 (256 B/row)
        agg_bf16_kernel<<<aggBlocks, 256, 0, stream>>>(xb, deg, offs, sortedSrc,
                                                       (unsigned int*)Aagg, N);
        gemm_kernel<<<gemmBlocks, 256, 0, stream>>>(Aagg, xb, Bpre, biasPre, h1b, 1, 0, 1, N);
        agg_bf16_kernel<<<aggBlocks, 256, 0, stream>>>((const unsigned int*)h1b, deg, offs,
                                                       sortedSrc, (unsigned int*)Aagg, N);
        gemm_kernel<<<gemmBlocks, 256, 0, stream>>>(Aagg, h1b, Bpre + 32768, biasPre + 128,
                                                    d_out, 0, 0, 0, N);
    } else {
        // Layout B: f32 gathers, h1 f32 staged in d_out
        float* h1 = (float*)d_out;
        agg_f32_kernel<<<aggBlocks, 256, 0, stream>>>(x, deg, offs, sortedSrc,
                                                      (unsigned int*)Aagg, N);
        gemm_kernel<<<gemmBlocks, 256, 0, stream>>>(Aagg, x, Bpre, biasPre, h1, 1, 1, 0, N);
        agg_f32_kernel<<<aggBlocks, 256, 0, stream>>>(h1, deg, offs, sortedSrc,
                                                      (unsigned int*)Aagg, N);
        gemm_kernel<<<gemmBlocks, 256, 0, stream>>>(Aagg, h1, Bpre + 32768, biasPre + 128,
                                                    d_out, 0, 1, 0, N);
    }
}